// Round 9
// baseline (263.478 us; speedup 1.0000x reference)
//
#include <hip/hip_runtime.h>
#include <hip/hip_bf16.h>
#include <cstdint>
#include <cstddef>

#define DEVINL __device__ __forceinline__

typedef __attribute__((ext_vector_type(4))) float   f32x4;
typedef __bf16 bf16x8 __attribute__((ext_vector_type(8)));
typedef __attribute__((ext_vector_type(4))) short   short4v;
typedef __attribute__((ext_vector_type(4))) float   float4v;

static constexpr int DIM = 1024;
static constexpr int NTOK = 4096;

// ---------- scalar helpers ----------
DEVINL unsigned short f2bf(float f) {
  unsigned u = __float_as_uint(f);
  u += 0x7FFF + ((u >> 16) & 1);
  return (unsigned short)(u >> 16);
}
DEVINL float bf2f(unsigned short s) {
  return __uint_as_float(((unsigned)s) << 16);
}

DEVINL void gll16(const void* g, void* l) {
  __builtin_amdgcn_global_load_lds(
      (const __attribute__((address_space(1))) void*)g,
      (__attribute__((address_space(3))) void*)l, 16, 0, 0);
}

// ---------- T1: bijective XCD chunk swizzle (nwg % 8 == 0 for all grids) ----------
struct B3 { int bx, by, bz; };
DEVINL B3 xcd_remap(int GX, int GY, int GZ) {
  const int flat = blockIdx.x + GX * (blockIdx.y + GY * blockIdx.z);
  const int nwg  = GX * GY * GZ;
  const int chunk = nwg >> 3;
  const int vbid = (flat & 7) * chunk + (flat >> 3);
  B3 r;
  r.bx = vbid % GX;
  r.by = (vbid / GX) % GY;
  r.bz = vbid / (GX * GY);
  return r;
}

// =====================================================================
// 128x128xK core, BK=64, 4 waves (2x2), 64 KB LDS double-buffer,
// 2 blocks/CU  <-- the round-9 change.
//
// WHY: staging-rate accounting across r2-r8 shows global_load_lds
// delivers ~8.7 B/cyc per resident BLOCK (all 1-block/CU variants pinned
// at ~5-6 TB/s chip-wide staging regardless of schedule). A 256^2 block
// needs 16 B/cyc to keep its MFMA floor -> starved. Two co-resident
// 128^2 blocks stage in parallel (~17 B/cyc/CU) and de-phase each
// other's barriers (cross-block MFMA/LDS overlap, m114 mechanism).
//
// Schedule per K-tile: {stage T+1 into buf^1 (8 gll16/thread) ; ds_read
// frags of buf^0 ; 32 MFMA/wave ; vmcnt(0) (stage issued a full tile
// ago -> latency hidden, only BW exposed, sibling block covers it) ;
// s_barrier}. Single barrier per K-tile is race-free: reads of buf b
// complete (lgkm-drained before their MFMA use) before the barrier;
// writes into buf b are issued only after that barrier.
// T2 swizzle: LDS[r][c] holds global col c ^ ((r&7)<<3) (0 conflicts,
// verified r3-r8).
// =====================================================================
DEVINL void core128(const unsigned short* __restrict__ A, int lda,
                    const unsigned short* __restrict__ B, int ldb,
                    int K, int brow, int bcol, f32x4 acc[4][4])
{
  __shared__ unsigned short lds[32768];   // 64 KB: buf b at b*16384; A +0, B +8192
  const int t = threadIdx.x;              // 0..255
  const int w = t >> 6, l = t & 63;
  const int wr = w >> 1, wc = w & 1;
  const int srow = (w << 3) + (l >> 3);                      // staging row 0..31 per r-group
  const int scol = ((l & 7) ^ (l >> 3)) << 3;                // inverse-swizzled source col
  const int l15 = l & 15;
  const int cs0 = (((l >> 4) << 3)        ^ ((l & 7) << 3)); // swizzled read col, ks=0
  const int cs1 = ((32 + ((l >> 4) << 3)) ^ ((l & 7) << 3)); // ks=1

  const unsigned short* aL = A + (size_t)(brow * 128 + srow) * lda + scol;
  const unsigned short* bL = B + (size_t)(bcol * 128 + srow) * ldb + scol;

#pragma unroll
  for (int m = 0; m < 4; ++m)
#pragma unroll
    for (int n = 0; n < 4; ++n) {
      f32x4 z = {0.f, 0.f, 0.f, 0.f};
      acc[m][n] = z;
    }

  // stage one K-tile (A 16KB + B 16KB): 8 gll16/thread; LDS dest wave-uniform.
#define STAGE(buf, kt)                                                         \
  _Pragma("unroll")                                                            \
  for (int r = 0; r < 4; ++r) {                                                \
    gll16(aL + (size_t)(r * 32) * lda + (size_t)(kt) * 64,                     \
          lds + (buf) * 16384 + (r * 32 + (w << 3)) * 64);                     \
    gll16(bL + (size_t)(r * 32) * ldb + (size_t)(kt) * 64,                     \
          lds + (buf) * 16384 + 8192 + (r * 32 + (w << 3)) * 64);              \
  }

#define BARR() do { asm volatile("" ::: "memory");                             \
                    __builtin_amdgcn_s_barrier();                              \
                    asm volatile("" ::: "memory"); } while (0)

  const int NT = K >> 6;

  STAGE(0, 0);
  asm volatile("s_waitcnt vmcnt(0)" ::: "memory");
  BARR();

  bf16x8 af[4][2], bfv[4][2];
  for (int kt = 0; kt < NT; ++kt) {
    const int cur = kt & 1;
    if (kt + 1 < NT) STAGE(cur ^ 1, kt + 1);

#pragma unroll
    for (int m = 0; m < 4; ++m) {
      const unsigned short* p = lds + cur * 16384 + (wr * 64 + m * 16 + l15) * 64;
      af[m][0] = *(const bf16x8*)(p + cs0);
      af[m][1] = *(const bf16x8*)(p + cs1);
    }
#pragma unroll
    for (int n = 0; n < 4; ++n) {
      const unsigned short* p = lds + cur * 16384 + 8192 + (wc * 64 + n * 16 + l15) * 64;
      bfv[n][0] = *(const bf16x8*)(p + cs0);
      bfv[n][1] = *(const bf16x8*)(p + cs1);
    }

    __builtin_amdgcn_s_setprio(1);
#pragma unroll
    for (int m = 0; m < 4; ++m)
#pragma unroll
      for (int n = 0; n < 4; ++n) {
        f32x4 c_ = acc[m][n];
        c_ = __builtin_amdgcn_mfma_f32_16x16x32_bf16(af[m][0], bfv[n][0], c_, 0, 0, 0);
        c_ = __builtin_amdgcn_mfma_f32_16x16x32_bf16(af[m][1], bfv[n][1], c_, 0, 0, 0);
        acc[m][n] = c_;
      }
    __builtin_amdgcn_s_setprio(0);

    asm volatile("s_waitcnt vmcnt(0)" ::: "memory");  // next buf landed
    BARR();
  }
#undef STAGE
#undef BARR
}

// ---------- scores: S = bf16( (A B^T) * scale ), [4096 x 4096] ----------
__global__ __launch_bounds__(256, 2)
void gemm128_scores(const unsigned short* __restrict__ A,
                    const unsigned short* __restrict__ B,
                    unsigned short* __restrict__ S, float scale)
{
  const B3 b = xcd_remap(32, 32, 1);
  f32x4 acc[4][4];
  core128(A, DIM, B, DIM, DIM, b.by, b.bx, acc);

  const int t = threadIdx.x, w = t >> 6, l = t & 63;
  const int wr = w >> 1, wc = w & 1;
  const int rr = (l >> 4) * 4, cc = l & 15;
#pragma unroll
  for (int m = 0; m < 4; ++m) {
    const int row0 = b.by * 128 + wr * 64 + m * 16 + rr;
#pragma unroll
    for (int n = 0; n < 4; ++n) {
      const int col = b.bx * 128 + wc * 64 + n * 16 + cc;
#pragma unroll
      for (int i = 0; i < 4; ++i)
        S[(size_t)(row0 + i) * NTOK + col] = f2bf(acc[m][n][i] * scale);
    }
  }
}

// ---------- merged QKV: grid.z = 6; v outputs transposed ----------
__global__ __launch_bounds__(256, 2)
void qkv128(const unsigned short* __restrict__ x1, const unsigned short* __restrict__ x2,
            const unsigned short* __restrict__ W6,
            const float* bq1, const float* bk1, const float* bv1,
            const float* bq2, const float* bk2, const float* bv2,
            unsigned short* q1, unsigned short* k1, unsigned short* v1T,
            unsigned short* q2, unsigned short* k2, unsigned short* v2T)
{
  const B3 b = xcd_remap(8, 32, 6);
  const int g = b.bz;
  const unsigned short* A = (g < 3) ? x1 : x2;
  const unsigned short* W = W6 + (size_t)g * (DIM * DIM);
  const float* bias = (g == 0) ? bq1 : (g == 1) ? bk1 : (g == 2) ? bv1
                    : (g == 3) ? bq2 : (g == 4) ? bk2 : bv2;
  unsigned short* out = (g == 0) ? q1 : (g == 1) ? k1 : (g == 2) ? v1T
                      : (g == 3) ? q2 : (g == 4) ? k2 : v2T;
  const bool vT = (g == 2 || g == 5);

  f32x4 acc[4][4];
  core128(A, DIM, W, DIM, DIM, b.by, b.bx, acc);

  const int t = threadIdx.x, w = t >> 6, l = t & 63;
  const int wr = w >> 1, wc = w & 1;
  const int rr = (l >> 4) * 4, cc = l & 15;

  if (!vT) {
#pragma unroll
    for (int m = 0; m < 4; ++m) {
      const int row0 = b.by * 128 + wr * 64 + m * 16 + rr;
#pragma unroll
      for (int n = 0; n < 4; ++n) {
        const int col = b.bx * 128 + wc * 64 + n * 16 + cc;
        const float bv_ = bias[col];
#pragma unroll
        for (int i = 0; i < 4; ++i)
          out[(size_t)(row0 + i) * DIM + col] = f2bf(acc[m][n][i] + bv_);
      }
    }
  } else {
    // transposed store: vT[d][token]; 4 consecutive tokens per lane -> 8B packed
#pragma unroll
    for (int m = 0; m < 4; ++m) {
      const int row0 = b.by * 128 + wr * 64 + m * 16 + rr;
#pragma unroll
      for (int n = 0; n < 4; ++n) {
        const int col = b.bx * 128 + wc * 64 + n * 16 + cc;
        const float bv_ = bias[col];
        short4v pk;
#pragma unroll
        for (int i = 0; i < 4; ++i) pk[i] = (short)f2bf(acc[m][n][i] + bv_);
        *(short4v*)(out + (size_t)col * NTOK + row0) = pk;
      }
    }
  }
}

// ---------- fused PV: C[4096 x 2048] = [P1@V1 | P2@V2], split-K=2 ----------
__global__ __launch_bounds__(256, 2)
void pv128(const unsigned short* __restrict__ S1,
           const unsigned short* __restrict__ S2,
           const unsigned short* __restrict__ vTcat,
           float* __restrict__ out, float* __restrict__ P)
{
  const B3 b = xcd_remap(16, 32, 2);
  const int bx = b.bx, by = b.by, z = b.bz;
  const unsigned short* A = ((bx < 8) ? S1 : S2) + (size_t)z * 2048;
  const unsigned short* B = vTcat + (size_t)z * 2048;

  f32x4 acc[4][4];
  core128(A, NTOK, B, NTOK, 2048, by, bx, acc);

  const int t = threadIdx.x, w = t >> 6, l = t & 63;
  const int wr = w >> 1, wc = w & 1;
  const int rr = (l >> 4) * 4, cc = l & 15;
#pragma unroll
  for (int m = 0; m < 4; ++m) {
    const int row0 = by * 128 + wr * 64 + m * 16 + rr;
#pragma unroll
    for (int n = 0; n < 4; ++n) {
      const int cg = bx * 128 + wc * 64 + n * 16 + cc;
#pragma unroll
      for (int i = 0; i < 4; ++i) {
        const int r = row0 + i;
        if (z) {
          P[(size_t)r * 2048 + cg] = acc[m][n][i];
        } else {
          float* dst = (cg < 1024) ? (out + (size_t)r * 1024 + cg)
                                   : (out + 4194304 + (size_t)r * 1024 + (cg - 1024));
          *dst = acc[m][n][i];
        }
      }
    }
  }
}

// out(+4M) += P, remapping [4096 x 2048] partial onto the two context halves
__global__ __launch_bounds__(256)
void add_pv(float* __restrict__ out, const float* __restrict__ P)
{
  const int idx = blockIdx.x * 256 + threadIdx.x;   // 2M threads, 4 floats each
  const int r  = idx >> 9;
  const int c4 = (idx & 511) << 2;
  const float4v p = *(const float4v*)(P + (size_t)r * 2048 + c4);
  float* dst = (c4 < 1024) ? (out + (size_t)r * 1024 + c4)
                           : (out + 4194304 + (size_t)r * 1024 + (c4 - 1024));
  float4v a = *(const float4v*)dst;
#pragma unroll
  for (int j = 0; j < 4; ++j) a[j] += p[j];
  *(float4v*)dst = a;
}

// ---------- row softmax, in place on bf16 [4096 x 4096] ----------
__global__ __launch_bounds__(256)
void softmax_inplace(unsigned short* __restrict__ S)
{
  const int row = blockIdx.x;
  unsigned short* r = S + (size_t)row * NTOK;
  const int t = threadIdx.x, wave = t >> 6, lane = t & 63;
  __shared__ float red[4];

  bf16x8 d0 = *(const bf16x8*)(r + t * 8);
  bf16x8 d1 = *(const bf16x8*)(r + 2048 + t * 8);
  float v[16];
  {
    const unsigned short* p0 = (const unsigned short*)&d0;
    const unsigned short* p1 = (const unsigned short*)&d1;
#pragma unroll
    for (int j = 0; j < 8; ++j) { v[j] = bf2f(p0[j]); v[8 + j] = bf2f(p1[j]); }
  }
  float mx = v[0];
#pragma unroll
  for (int j = 1; j < 16; ++j) mx = fmaxf(mx, v[j]);
#pragma unroll
  for (int o = 32; o > 0; o >>= 1) mx = fmaxf(mx, __shfl_xor(mx, o));
  if (lane == 0) red[wave] = mx;
  __syncthreads();
  mx = fmaxf(fmaxf(red[0], red[1]), fmaxf(red[2], red[3]));

  float s = 0.f;
#pragma unroll
  for (int j = 0; j < 16; ++j) { v[j] = __expf(v[j] - mx); s += v[j]; }
#pragma unroll
  for (int o = 32; o > 0; o >>= 1) s += __shfl_xor(s, o);
  __syncthreads();
  if (lane == 0) red[wave] = s;
  __syncthreads();
  s = red[0] + red[1] + red[2] + red[3];
  const float inv = 1.0f / s;

  unsigned short o0[8], o1[8];
#pragma unroll
  for (int j = 0; j < 8; ++j) { o0[j] = f2bf(v[j] * inv); o1[j] = f2bf(v[8 + j] * inv); }
  *(bf16x8*)(r + t * 8)        = *(const bf16x8*)o0;
  *(bf16x8*)(r + 2048 + t * 8) = *(const bf16x8*)o1;
}

// ---------- fp32 -> bf16 converters ----------
__global__ __launch_bounds__(256)
void cvt2(const float* __restrict__ a, const float* __restrict__ b,
          unsigned short* __restrict__ oa, unsigned short* __restrict__ ob)
{
  const float* in = blockIdx.y ? b : a;
  unsigned short* out = blockIdx.y ? ob : oa;
  const size_t i = ((size_t)blockIdx.x * 256 + threadIdx.x) * 4;
  float4v x = *(const float4v*)(in + i);
  short4v o;
#pragma unroll
  for (int j = 0; j < 4; ++j) o[j] = (short)f2bf(x[j]);
  *(short4v*)(out + i) = o;
}

__global__ __launch_bounds__(256)
void cvt_w(const float* w0, const float* w1, const float* w2,
           const float* w3, const float* w4, const float* w5,
           unsigned short* __restrict__ W6)
{
  const float* srcs[6] = {w0, w1, w2, w3, w4, w5};
  const float* in = srcs[blockIdx.y];
  unsigned short* out = W6 + (size_t)blockIdx.y * (DIM * DIM);
  const size_t i = ((size_t)blockIdx.x * 256 + threadIdx.x) * 4;
  float4v x = *(const float4v*)(in + i);
  short4v o;
#pragma unroll
  for (int j = 0; j < 4; ++j) o[j] = (short)f2bf(x[j]);
  *(short4v*)(out + i) = o;
}

// ---------- host launcher ----------
extern "C" void kernel_launch(void* const* d_in, const int* in_sizes, int n_in,
                              void* d_out, int out_size, void* d_ws, size_t ws_size,
                              hipStream_t stream)
{
  const float* x1  = (const float*)d_in[0];
  const float* x2  = (const float*)d_in[1];
  const float* Wq1 = (const float*)d_in[2];  const float* bq1 = (const float*)d_in[3];
  const float* Wk1 = (const float*)d_in[4];  const float* bk1 = (const float*)d_in[5];
  const float* Wv1 = (const float*)d_in[6];  const float* bv1 = (const float*)d_in[7];
  const float* Wq2 = (const float*)d_in[8];  const float* bq2 = (const float*)d_in[9];
  const float* Wk2 = (const float*)d_in[10]; const float* bk2 = (const float*)d_in[11];
  const float* Wv2 = (const float*)d_in[12]; const float* bv2 = (const float*)d_in[13];
  float* out = (float*)d_out;

  // ws layout (ushort units):
  //  [0,16M):    x1b(4M) x2b(4M) W6(6M) pad -> later S1 [4096x4096]
  //  [16M,32M):  S2
  //  [32M,48M):  q1 k1 q2 k2 (4M each)      -> later P (fp32 partial, 32 MB)
  //  [48M,56M):  v1T v2T (vTcat, [2048 x 4096])
  unsigned short* ws  = (unsigned short*)d_ws;
  const size_t NTD = (size_t)NTOK * DIM;           // 4M elems
  const size_t SM  = (size_t)NTOK * NTOK;          // 16M elems
  unsigned short* x1b = ws;
  unsigned short* x2b = x1b + NTD;
  unsigned short* W6  = x2b + NTD;
  unsigned short* S1  = ws;
  unsigned short* S2  = ws + SM;
  unsigned short* q1  = ws + 2 * SM;
  unsigned short* k1  = q1 + NTD;
  unsigned short* q2  = k1 + NTD;
  unsigned short* k2  = q2 + NTD;
  unsigned short* vT  = k2 + NTD;                  // v1T followed by v2T
  unsigned short* v1T = vT;
  unsigned short* v2T = vT + NTD;
  float* P = (float*)q1;                           // 32 MB partial over dead q/k

  const dim3 blk(256);
  cvt2 <<<dim3(NTD / 1024, 2), blk, 0, stream>>>(x1, x2, x1b, x2b);
  cvt_w<<<dim3((DIM * DIM) / 1024, 6), blk, 0, stream>>>(Wq1, Wk1, Wv1, Wq2, Wk2, Wv2, W6);

  qkv128<<<dim3(8, 32, 6), blk, 0, stream>>>(
      x1b, x2b, W6, bq1, bk1, bv1, bq2, bk2, bv2, q1, k1, v1T, q2, k2, v2T);

  const float scale = 0.03125f;  // 1/sqrt(1024)

  // scores + softmax (S1 overwrites dead x/W region)
  gemm128_scores<<<dim3(32, 32), blk, 0, stream>>>(q2, k1, S1, scale);
  softmax_inplace<<<dim3(NTOK), blk, 0, stream>>>(S1);
  gemm128_scores<<<dim3(32, 32), blk, 0, stream>>>(q1, k2, S2, scale);
  softmax_inplace<<<dim3(NTOK), blk, 0, stream>>>(S2);

  // fused PV over [v1T; v2T], split-K=2 (q/k region now dead -> P)
  pv128<<<dim3(16, 32, 2), blk, 0, stream>>>(S1, S2, vT, out, P);
  add_pv<<<dim3(8192), blk, 0, stream>>>(out, P);
}